// Round 15
// baseline (26.540 us; speedup 1.0000x reference)
//
#include <hip/hip_runtime.h>

#define NB   8
#define NDEP 64
#define KK   512
#define NP   12
#define NT   550
#define L2E  1.4426950408889634f
#define GN   3.9894228040143274f

static __device__ __forceinline__ float fast_rcp(float x) {
    return __builtin_amdgcn_rcpf(x);
}

// 32 rows per wave. LDS row k at dword offset k*16 + (k>>4)*4 (16B pad per
// 16 rows): concurrent sub reads land on distinct bank groups.
// Gather over this wave's 32 rows, shuffle-combine subs, per-wave atomics.
template<int S>
static __device__ __forceinline__ void gather_reduce32(
    const float* __restrict__ wl, int lane, int t_lo, int b,
    float* __restrict__ out)
{
    constexpr int W  = 64 / S;     // t-stations
    constexpr int IT = 32 / S;     // rows per sub
    const int tw  = lane & (W - 1);
    const int sub = lane / W;
    const float tc = (float)t_lo + (float)tw + 0.5f;

    float acc[NP];
    #pragma unroll
    for (int p = 0; p < NP; ++p) acc[p] = 0.0f;

    #pragma unroll 4
    for (int i = 0; i < IT; ++i) {
        const int k = sub * IT + i;
        const int o = (k << 4) + ((k >> 4) << 2);
        const float4 r0 = *(const float4*)&wl[o];
        const float4 r1 = *(const float4*)&wl[o + 4];
        const float4 r2 = *(const float4*)&wl[o + 8];
        const float ez  = wl[o + 12];
        const float d   = tc - ez;
        const float g   = exp2f(-14.426950408889634f * d * d);   // exp(-10 d^2)
        acc[0]  = fmaf(r0.x, g, acc[0]);  acc[1]  = fmaf(r0.y, g, acc[1]);
        acc[2]  = fmaf(r0.z, g, acc[2]);  acc[3]  = fmaf(r0.w, g, acc[3]);
        acc[4]  = fmaf(r1.x, g, acc[4]);  acc[5]  = fmaf(r1.y, g, acc[5]);
        acc[6]  = fmaf(r1.z, g, acc[6]);  acc[7]  = fmaf(r1.w, g, acc[7]);
        acc[8]  = fmaf(r2.x, g, acc[8]);  acc[9]  = fmaf(r2.y, g, acc[9]);
        acc[10] = fmaf(r2.z, g, acc[10]); acc[11] = fmaf(r2.w, g, acc[11]);
    }

    #pragma unroll
    for (int msk = W; msk < 64; msk <<= 1) {
        #pragma unroll
        for (int p = 0; p < NP; ++p) acc[p] += __shfl_xor(acc[p], msk);
    }

    if (lane < W) {
        float* ob = out + ((size_t)b * NP) * NT + (t_lo + tw);
        #pragma unroll
        for (int p = 0; p < NP; ++p) atomicAdd(&ob[p * NT], acc[p]);
    }
}

__global__ __launch_bounds__(256) void next_sim_wave(
    const float* __restrict__ ed,      // (8,64,4) x,y,z,E
    const float* __restrict__ edraw,   // (8,64)
    const float* __restrict__ ddraw,   // (8,64,512,3)
    const float* __restrict__ udraw,   // (8,64,512)
    const float* __restrict__ W1, const float* __restrict__ b1,
    const float* __restrict__ W2, const float* __restrict__ b2,
    const float* __restrict__ dscale, const float* __restrict__ pscale,
    const float* __restrict__ life,
    float* __restrict__ out)           // (8,12,550)
{
    __shared__ float rows[4][528];     // per-wave private: 32 rows x 16 + pad (8.4 KB)

    const int tid  = threadIdx.x;
    const int lane = tid & 63;
    const int wid  = tid >> 6;             // 0..3
    const int bid  = blockIdx.x;           // 2048 blocks: bn*4 + kquarter
    const int bn   = bid >> 2;
    const int g32  = ((bid & 3) << 2) | wid;   // k-group-of-32, 0..15
    const int b    = bn >> 6;

    // hoisted per-lane loads (lane halves duplicate -> same cache lines)
    const float4 dep = ((const float4*)ed)[bn];
    const float  edr = edraw[bn];
    const int    kl  = lane & 31;
    const int    k   = (g32 << 5) + kl;
    const float* dd  = ddraw + ((size_t)bn * KK + k) * 3;
    const float d0 = dd[0], d1 = dd[1], d2 = dd[2];
    const float u  = udraw[(size_t)bn * KK + k];

    // wave-uniform header
    const float nval  = dep.w * (1000000.0f / 22.4f);
    const float sigma = sqrtf(0.15f * nval);
    int ne = (int)(sigma * edr + nval);    // trunc == astype(int32)
    ne = min(max(ne, 0), KK);
    if ((g32 << 5) >= ne) return;          // dead wave: early exit

    const float sqz     = sqrtf(dep.z);
    const float invLife = fast_rcp(life[0]);
    const float dS0 = dscale[0] * dscale[0];
    const float dS1 = dscale[1] * dscale[1];
    const float dS2 = dscale[2] * dscale[2];

    const float ez = fmaf(dS2 * d2, sqz, dep.z);
    const float ex = fmaf(dS0 * d0, sqz, dep.x);
    const float ey = fmaf(dS1 * d1, sqz, dep.y);
    const float prob = 1.0f - __expf(-ez * invLife);
    const float m = ((k < ne) && (prob > u)) ? 1.0f : 0.0f;

    // MLP, all f32; weights via uniform-index global loads (s_load, L2-hot)
    float pm[NP];
    #pragma unroll
    for (int p = 0; p < NP; ++p) pm[p] = b2[p];
    #pragma unroll 4
    for (int j = 0; j < 28; ++j) {
        const float lg = fmaf(W1[j], ex, fmaf(W1[28 + j], ey, b1[j]));
        const float hj = fast_rcp(1.0f + exp2f(-lg * L2E));
        #pragma unroll
        for (int p = 0; p < NP; ++p) pm[p] = fmaf(hj, W2[j * NP + p], pm[p]);
    }
    const float gm = GN * m;               // fold GAUSS_NORM + mask
    float q[NP];
    #pragma unroll
    for (int p = 0; p < NP; ++p)
        q[p] = pscale[p] * pscale[p] * gm * fast_rcp(1.0f + exp2f(-pm[p] * L2E));

    // lanes 0..31 write the wave's 32 f32 rows
    float* wl = rows[wid];
    if (lane < 32) {
        const int off = (kl << 4) + ((kl >> 4) << 2);
        *(float4*)&wl[off]     = make_float4(q[0], q[1],  q[2],  q[3]);
        *(float4*)&wl[off + 4] = make_float4(q[4], q[5],  q[6],  q[7]);
        *(float4*)&wl[off + 8] = make_float4(q[8], q[9],  q[10], q[11]);
        wl[off + 12] = ez;
    }

    // wave ez min/max -> adaptive window
    float ezmin = ez, ezmax = ez;
    #pragma unroll
    for (int msk = 1; msk < 64; msk <<= 1) {
        ezmin = fminf(ezmin, __shfl_xor(ezmin, msk));
        ezmax = fmaxf(ezmax, __shfl_xor(ezmax, msk));
    }
    const int fmin = (int)floorf(ezmin);
    const int fmax = (int)floorf(ezmax);
    const int need = fmax - fmin + 7;      // +-3 ticks around [fmin, fmax]

    if (need <= 16) {
        const int t_lo = min(max(fmin - 3, 0), NT - 16);
        gather_reduce32<4>(wl, lane, t_lo, b, out);
    } else {
        const int t_lo = min(max(fmin - 3, 0), NT - 32);
        gather_reduce32<2>(wl, lane, t_lo, b, out);
    }
}

extern "C" void kernel_launch(void* const* d_in, const int* in_sizes, int n_in,
                              void* d_out, int out_size, void* d_ws, size_t ws_size,
                              hipStream_t stream) {
    const float* ed     = (const float*)d_in[0];
    const float* edraw  = (const float*)d_in[1];
    const float* ddraw  = (const float*)d_in[2];
    const float* udraw  = (const float*)d_in[3];
    const float* W1     = (const float*)d_in[4];
    const float* b1     = (const float*)d_in[5];
    const float* W2     = (const float*)d_in[6];
    const float* b2     = (const float*)d_in[7];
    const float* dscale = (const float*)d_in[8];
    const float* pscale = (const float*)d_in[9];
    const float* life   = (const float*)d_in[10];
    float* out = (float*)d_out;

    hipMemsetAsync(d_out, 0, (size_t)out_size * sizeof(float), stream);
    next_sim_wave<<<NB * NDEP * 4, 256, 0, stream>>>(
        ed, edraw, ddraw, udraw, W1, b1, W2, b2, dscale, pscale, life, out);
}

// Round 17
// 20.201 us; speedup vs baseline: 1.3138x; 1.3138x over previous
//
#include <hip/hip_runtime.h>

#define NB   8
#define NDEP 64
#define KK   512
#define NP   12
#define NT   550
#define L2E  1.4426950408889634f
#define GN   3.9894228040143274f

static __device__ __forceinline__ float fast_rcp(float x) {
    return __builtin_amdgcn_rcpf(x);
}

// LDS row k at dword offset k*16 + (k>>4)*4 (16B pad per 16 rows): the S
// concurrent sub reads land on distinct bank groups.
// Gather over this wave's 64 rows, shuffle-combine subs, per-wave atomics.
template<int S>
static __device__ __forceinline__ void gather_reduce(
    const float* __restrict__ wl, int lane, int t_lo, int b,
    float* __restrict__ out)
{
    constexpr int W = 64 / S;
    const int tw  = lane & (W - 1);
    const int sub = lane / W;
    const float tc = (float)t_lo + (float)tw + 0.5f;

    float acc[NP];
    #pragma unroll
    for (int p = 0; p < NP; ++p) acc[p] = 0.0f;

    #pragma unroll 4
    for (int i = 0; i < W; ++i) {
        const int k = sub * W + i;
        const int o = (k << 4) + ((k >> 4) << 2);
        const float4 r0 = *(const float4*)&wl[o];
        const float4 r1 = *(const float4*)&wl[o + 4];
        const float4 r2 = *(const float4*)&wl[o + 8];
        const float ez  = wl[o + 12];
        const float d   = tc - ez;
        const float g   = exp2f(-14.426950408889634f * d * d);   // exp(-10 d^2)
        acc[0]  = fmaf(r0.x, g, acc[0]);  acc[1]  = fmaf(r0.y, g, acc[1]);
        acc[2]  = fmaf(r0.z, g, acc[2]);  acc[3]  = fmaf(r0.w, g, acc[3]);
        acc[4]  = fmaf(r1.x, g, acc[4]);  acc[5]  = fmaf(r1.y, g, acc[5]);
        acc[6]  = fmaf(r1.z, g, acc[6]);  acc[7]  = fmaf(r1.w, g, acc[7]);
        acc[8]  = fmaf(r2.x, g, acc[8]);  acc[9]  = fmaf(r2.y, g, acc[9]);
        acc[10] = fmaf(r2.z, g, acc[10]); acc[11] = fmaf(r2.w, g, acc[11]);
    }

    #pragma unroll
    for (int msk = W; msk < 64; msk <<= 1) {
        #pragma unroll
        for (int p = 0; p < NP; ++p) acc[p] += __shfl_xor(acc[p], msk);
    }

    if (lane < W) {
        float* ob = out + ((size_t)b * NP) * NT + (t_lo + tw);
        #pragma unroll
        for (int p = 0; p < NP; ++p) atomicAdd(&ob[p * NT], acc[p]);
    }
}

__global__ __launch_bounds__(256) void next_sim_wave(
    const float* __restrict__ ed,      // (8,64,4) x,y,z,E
    const float* __restrict__ edraw,   // (8,64)
    const float* __restrict__ ddraw,   // (8,64,512,3)
    const float* __restrict__ udraw,   // (8,64,512)
    const float* __restrict__ W1, const float* __restrict__ b1,
    const float* __restrict__ W2, const float* __restrict__ b2,
    const float* __restrict__ dscale, const float* __restrict__ pscale,
    const float* __restrict__ life,
    float* __restrict__ out)           // (8,12,550)
{
    __shared__ float rows[4][1040];    // per-wave private f32 rows (16.6 KB)

    const int tid  = threadIdx.x;
    const int lane = tid & 63;
    const int wid  = tid >> 6;             // 0..3
    const int bid  = blockIdx.x;           // 1024 blocks: bn*2 + khalf
    const int bn   = bid >> 1;
    const int g    = ((bid & 1) << 2) | wid;   // k-group 0..7
    const int b    = bn >> 6;

    // hoisted per-lane loads
    const float4 dep = ((const float4*)ed)[bn];
    const float  edr = edraw[bn];
    const int    k   = (g << 6) + lane;
    const float* dd  = ddraw + ((size_t)bn * KK + k) * 3;
    const float d0 = dd[0], d1 = dd[1], d2 = dd[2];
    const float u  = udraw[(size_t)bn * KK + k];

    // wave-uniform header
    const float nval  = dep.w * (1000000.0f / 22.4f);
    const float sigma = sqrtf(0.15f * nval);
    int ne = (int)(sigma * edr + nval);    // trunc == astype(int32)
    ne = min(max(ne, 0), KK);
    if ((g << 6) >= ne) return;            // dead wave: early exit

    const float sqz     = sqrtf(dep.z);
    const float cLife   = -fast_rcp(life[0]) * L2E;   // surv test: exp2(ez*cLife) < 1-u
    const float dS0 = dscale[0] * dscale[0];
    const float dS1 = dscale[1] * dscale[1];
    const float dS2 = dscale[2] * dscale[2];

    const float ez = fmaf(dS2 * d2, sqz, dep.z);
    const float ex = fmaf(dS0 * d0, sqz, dep.x);
    const float ey = fmaf(dS1 * d1, sqz, dep.y);
    // prob > u  <=>  1 - exp2(ez*cLife) > u  <=>  exp2(ez*cLife) < 1-u
    const float m = ((k < ne) && (exp2f(ez * cLife) < 1.0f - u)) ? 1.0f : 0.0f;

    // MLP, all f32; weights via uniform-index global loads (s_load, L2-hot).
    // unroll 7: batches two j-groups of W2 s_loads ahead of their use.
    float pm[NP];
    #pragma unroll
    for (int p = 0; p < NP; ++p) pm[p] = b2[p];
    #pragma unroll 7
    for (int j = 0; j < 28; ++j) {
        const float lg = fmaf(W1[j], ex, fmaf(W1[28 + j], ey, b1[j]));
        const float hj = fast_rcp(1.0f + exp2f(-lg * L2E));
        #pragma unroll
        for (int p = 0; p < NP; ++p) pm[p] = fmaf(hj, W2[j * NP + p], pm[p]);
    }
    const float gm = GN * m;               // fold GAUSS_NORM + mask
    float q[NP];
    #pragma unroll
    for (int p = 0; p < NP; ++p)
        q[p] = pscale[p] * pscale[p] * gm * fast_rcp(1.0f + exp2f(-pm[p] * L2E));

    // this lane's f32 row into the wave-private LDS region
    float* wl = rows[wid];
    const int off = (lane << 4) + ((lane >> 4) << 2);
    *(float4*)&wl[off]     = make_float4(q[0], q[1],  q[2],  q[3]);
    *(float4*)&wl[off + 4] = make_float4(q[4], q[5],  q[6],  q[7]);
    *(float4*)&wl[off + 8] = make_float4(q[8], q[9],  q[10], q[11]);
    wl[off + 12] = ez;

    // wave ez min/max -> adaptive window
    float ezmin = ez, ezmax = ez;
    #pragma unroll
    for (int msk = 1; msk < 64; msk <<= 1) {
        ezmin = fminf(ezmin, __shfl_xor(ezmin, msk));
        ezmax = fmaxf(ezmax, __shfl_xor(ezmax, msk));
    }
    const int fmin = (int)floorf(ezmin);
    const int fmax = (int)floorf(ezmax);
    const int need = fmax - fmin + 7;      // +-3 ticks around [fmin, fmax]

    if (need <= 16) {
        const int t_lo = min(max(fmin - 3, 0), NT - 16);
        gather_reduce<4>(wl, lane, t_lo, b, out);
    } else {
        const int t_lo = min(max(fmin - 3, 0), NT - 32);
        gather_reduce<2>(wl, lane, t_lo, b, out);
    }
}

extern "C" void kernel_launch(void* const* d_in, const int* in_sizes, int n_in,
                              void* d_out, int out_size, void* d_ws, size_t ws_size,
                              hipStream_t stream) {
    const float* ed     = (const float*)d_in[0];
    const float* edraw  = (const float*)d_in[1];
    const float* ddraw  = (const float*)d_in[2];
    const float* udraw  = (const float*)d_in[3];
    const float* W1     = (const float*)d_in[4];
    const float* b1     = (const float*)d_in[5];
    const float* W2     = (const float*)d_in[6];
    const float* b2     = (const float*)d_in[7];
    const float* dscale = (const float*)d_in[8];
    const float* pscale = (const float*)d_in[9];
    const float* life   = (const float*)d_in[10];
    float* out = (float*)d_out;

    hipMemsetAsync(d_out, 0, (size_t)out_size * sizeof(float), stream);
    next_sim_wave<<<NB * NDEP * 2, 256, 0, stream>>>(
        ed, edraw, ddraw, udraw, W1, b1, W2, b2, dscale, pscale, life, out);
}